// Round 4
// baseline (667.771 us; speedup 1.0000x reference)
//
#include <hip/hip_runtime.h>
#include <hip/hip_cooperative_groups.h>
#include <hip/hip_fp16.h>
#include <cstdint>
#include <cstddef>

#define NEG_SLOPE 0.2f
#define LN_EPS 1e-5f

constexpr int BS = 256;
constexpr int STRIDE = 96;   // slots per dst node; slot 0 reserved for the self-loop,
                             // edges append from 1 via atomicAdd. Poisson(12) in-degree
                             // -> max ~40 for this dataset. Multiple of 16.

typedef _Float16 f16x8 __attribute__((ext_vector_type(8)));
typedef float f32x4 __attribute__((ext_vector_type(4)));

struct MegaArgs {
    const int* esrc; const int* edst;
    int* cnt; unsigned short* sn;
    const float* x; const int* cid; const float* emb;
    _Float16* xb;
    const float* W1; const float* W2;
    _Float16* Wt1; _Float16* Wt2;
    const float* as1; const float* ad1; const float* b1;
    const float* lng; const float* lnb;
    const float* as2; const float* ad2; const float* b2;
    _Float16* yb; _Float16* hb; float* fas; float* fad;
    float* out;
    int e, n, npad;
};

// ============================ GEMM phase (device fn) ============================
// 4 waves/block, each wave 16 rows x 64 cols; grid-stride over row tiles.
// Lane owns 4 consecutive cols of one row per s-tile; as_/ad_ row-dots combined
// across the 2 col-half waves via a tiny LDS reduction.
template<int KP>
__device__ __forceinline__ void gemm_phase(
    const _Float16* __restrict__ A, const _Float16* __restrict__ Bt,
    const float* __restrict__ a_src, const float* __restrict__ a_dst,
    _Float16* __restrict__ hb, float* __restrict__ as_,
    float* __restrict__ ad_, int n)
{
    __shared__ float red[2][16][2][2];   // [rowgrp][r15][colhalf][vs/vd]
    int tid = threadIdx.x;
    int wave = tid >> 6, lane = tid & 63;
    int rg = wave >> 1, ch = wave & 1;
    int r15 = lane & 15, q = lane >> 4;
    int colBase = ch * 64;
    int nt = (n + 31) / 32;

    for (int t = blockIdx.x; t < nt; t += gridDim.x) {
        int rowBase = t * 32 + rg * 16;

        f32x4 acc[4] = {};
        const _Float16* Wp[4];
        #pragma unroll
        for (int s = 0; s < 4; ++s)
            Wp[s] = Bt + (size_t)(colBase + s * 16 + r15) * KP + q * 8;
        const _Float16* Xp = A + (size_t)(rowBase + r15) * KP + q * 8;

        #pragma unroll
        for (int k0 = 0; k0 < KP; k0 += 32) {
            f16x8 wv[4];
            #pragma unroll
            for (int s = 0; s < 4; ++s) wv[s] = *(const f16x8*)(Wp[s] + k0);
            f16x8 xv = *(const f16x8*)(Xp + k0);
            #pragma unroll
            for (int s = 0; s < 4; ++s)
                acc[s] = __builtin_amdgcn_mfma_f32_16x16x32_f16(wv[s], xv, acc[s], 0, 0, 0);
        }

        int row = rowBase + r15;
        bool ok = row < n;
        float vs = 0.f, vd = 0.f;
        #pragma unroll
        for (int s = 0; s < 4; ++s) {
            float4 as4 = *(const float4*)&a_src[colBase + s * 16 + q * 4];
            float4 ad4 = *(const float4*)&a_dst[colBase + s * 16 + q * 4];
            f32x4 d = acc[s];
            vs += d[0]*as4.x + d[1]*as4.y + d[2]*as4.z + d[3]*as4.w;
            vd += d[0]*ad4.x + d[1]*ad4.y + d[2]*ad4.z + d[3]*ad4.w;
            if (ok) {
                ushort4 u;
                u.x = __half_as_ushort(__float2half_rn(d[0]));
                u.y = __half_as_ushort(__float2half_rn(d[1]));
                u.z = __half_as_ushort(__float2half_rn(d[2]));
                u.w = __half_as_ushort(__float2half_rn(d[3]));
                *(ushort4*)&hb[(size_t)row * 128 + colBase + s * 16 + q * 4] = u;
            }
        }
        vs += __shfl_xor(vs, 16); vs += __shfl_xor(vs, 32);
        vd += __shfl_xor(vd, 16); vd += __shfl_xor(vd, 32);
        __syncthreads();                       // WAR vs previous iteration's red reads
        if (q == 0) { red[rg][r15][ch][0] = vs; red[rg][r15][ch][1] = vd; }
        __syncthreads();
        if (ch == 0 && q == 0 && ok) {
            as_[row] = red[rg][r15][0][0] + red[rg][r15][1][0];
            ad_[row] = red[rg][r15][0][1] + red[rg][r15][1][1];
        }
    }
}

// ============================ aggregation phase (device fn) ============================
// one wave per dst node (grid-stride over groups of 4); quarter-wave layout:
// lane l4 owns channels [8*l4, 8*l4+8); quarters process 4 edges per gather.
// Edge weights computed inline. start = n*STRIDE, len = cnt[n] (self at slot 0).
template<bool LN_ELU, bool OUT_HALF>
__device__ __forceinline__ void agg_phase(
    const _Float16* __restrict__ hb, const unsigned short* __restrict__ sn,
    const int* __restrict__ cnt, const float* __restrict__ as_,
    const float* __restrict__ ad_, const float* __restrict__ bias,
    const float* __restrict__ ln_g, const float* __restrict__ ln_b,
    void* __restrict__ outv, int n_nodes)
{
    int wave = threadIdx.x >> 6, lane = threadIdx.x & 63;
    int l4 = lane & 15, q = lane >> 4;
    const char* hbB = (const char*)hb;
    int ng = (n_nodes + 3) >> 2;

    for (int g = blockIdx.x; g < ng; g += gridDim.x) {
        int n = g * 4 + wave;
        if (n >= n_nodes) continue;
        int len = cnt[n];
        len = len < STRIDE ? len : STRIDE;
        len = __builtin_amdgcn_readfirstlane(len);
        int start = n * STRIDE;
        float adv = ad_[n];

        float acc[8] = {0.f, 0.f, 0.f, 0.f, 0.f, 0.f, 0.f, 0.f};
        float dsum = 0.f;
        for (int j = 0; j < len; j += 16) {
            int rem = len - j;                      // uniform
            int offB = (l4 < rem) ? ((int)sn[start + j + l4] << 8) : 0;
            float t = as_[offB >> 8] + adv;         // inline weight
            t = t > 0.f ? t : NEG_SLOPE * t;
            float w0 = __expf(fminf(t, 70.f));
            #pragma unroll
            for (int v = 0; v < 4; ++v) {
                int e = 4 * v + q;                  // this lane's edge
                int ob  = __shfl(offB, e);
                float w = __shfl(w0, e);
                if (e < rem) {                      // quarter-uniform: skip dead gathers
                    f16x8 hv = *(const f16x8*)(hbB + ob + l4 * 16);
                    #pragma unroll
                    for (int c = 0; c < 8; ++c)
                        acc[c] = fmaf(w, (float)hv[c], acc[c]);
                    dsum += w;
                }
            }
        }
        #pragma unroll
        for (int c = 0; c < 8; ++c) {
            acc[c] += __shfl_xor(acc[c], 16);
            acc[c] += __shfl_xor(acc[c], 32);
        }
        dsum += __shfl_xor(dsum, 16);
        dsum += __shfl_xor(dsum, 32);

        float inv = 1.f / dsum;
        float4 b0 = *(const float4*)&bias[l4 * 8];
        float4 b1 = *(const float4*)&bias[l4 * 8 + 4];
        float vv[8];
        vv[0] = acc[0] * inv + b0.x; vv[1] = acc[1] * inv + b0.y;
        vv[2] = acc[2] * inv + b0.z; vv[3] = acc[3] * inv + b0.w;
        vv[4] = acc[4] * inv + b1.x; vv[5] = acc[5] * inv + b1.y;
        vv[6] = acc[6] * inv + b1.z; vv[7] = acc[7] * inv + b1.w;

        if (LN_ELU) {
            float s1 = 0.f, s2 = 0.f;
            #pragma unroll
            for (int c = 0; c < 8; ++c) { s1 += vv[c]; s2 += vv[c] * vv[c]; }
            #pragma unroll
            for (int o = 1; o < 16; o <<= 1) {
                s1 += __shfl_xor(s1, o);
                s2 += __shfl_xor(s2, o);
            }
            float mean = s1 * (1.f / 128.f);
            float var  = s2 * (1.f / 128.f) - mean * mean;
            float r = rsqrtf(var + LN_EPS);
            float4 g0 = *(const float4*)&ln_g[l4 * 8];
            float4 g1 = *(const float4*)&ln_g[l4 * 8 + 4];
            float4 p0 = *(const float4*)&ln_b[l4 * 8];
            float4 p1 = *(const float4*)&ln_b[l4 * 8 + 4];
            float gg[8] = {g0.x, g0.y, g0.z, g0.w, g1.x, g1.y, g1.z, g1.w};
            float pp[8] = {p0.x, p0.y, p0.z, p0.w, p1.x, p1.y, p1.z, p1.w};
            #pragma unroll
            for (int c = 0; c < 8; ++c) {
                float t = (vv[c] - mean) * r * gg[c] + pp[c];
                vv[c] = t > 0.f ? t : __expf(t) - 1.f;   // ELU
            }
        }

        if (q == 0) {
            if (OUT_HALF) {
                _Float16* out = (_Float16*)outv;
                f16x8 o;
                #pragma unroll
                for (int c = 0; c < 8; ++c) o[c] = (_Float16)vv[c];
                *(f16x8*)(out + (size_t)n * 128 + l4 * 8) = o;
            } else {
                float* out = (float*)outv;
                float4 o0 = make_float4(vv[0], vv[1], vv[2], vv[3]);
                float4 o1 = make_float4(vv[4], vv[5], vv[6], vv[7]);
                *(float4*)(out + (size_t)n * 128 + l4 * 8)     = o0;
                *(float4*)(out + (size_t)n * 128 + l4 * 8 + 4) = o1;
            }
        }
    }
}

// ============================ build phases (device fns) ============================
__device__ __forceinline__ void init_phase(MegaArgs& a, int gtid, int gsz) {
    // cnt=1 reserves slot 0 for the self-loop (no atomic needed for it)
    for (int i = gtid; i < a.n; i += gsz) {
        a.cnt[i] = 1;
        a.sn[(size_t)i * STRIDE] = (unsigned short)i;
    }
}

__device__ __forceinline__ void build_phase(MegaArgs& a, int gtid, int gsz) {
    // edge scatter: one atomic per real edge (self-loops pre-placed)
    for (int i = gtid; i < a.e; i += gsz) {
        int s = a.esrc[i], d = a.edst[i];
        int slot = atomicAdd(&a.cnt[d], 1);
        if (slot < STRIDE)                     // safety clamp (unreachable for this data)
            a.sn[(size_t)d * STRIDE + slot] = (unsigned short)s;
    }
    // xb fp16 staging (x_base | emb | zero pad), 32 threads per row
    {
        int c = gtid & 31;
        for (int r = gtid >> 5; r < a.npad; r += gsz >> 5) {
            _Float16* row = a.xb + (size_t)r * 160;
            if (r < a.n) {
                const float* xr = a.x + (size_t)r * 128;
                #pragma unroll
                for (int k = 0; k < 4; ++k) row[c + 32 * k] = (_Float16)xr[c + 32 * k];
                float v = (c < 8) ? a.emb[a.cid[r] * 8 + c] : 0.f;
                row[128 + c] = (_Float16)v;
            } else {
                #pragma unroll
                for (int k = 0; k < 5; ++k) row[c + 32 * k] = (_Float16)0.f;
            }
        }
    }
    // weight transposes
    for (int idx = gtid; idx < 128 * 160 + 128 * 128; idx += gsz) {
        if (idx < 128 * 160) {
            int nn = idx / 160, k = idx - nn * 160;
            a.Wt1[idx] = (_Float16)((k < 136) ? a.W1[(size_t)k * 128 + nn] : 0.f);
        } else {
            int j = idx - 128 * 160;
            int nn = j >> 7, k = j & 127;
            a.Wt2[j] = (_Float16)a.W2[(size_t)k * 128 + nn];
        }
    }
}

// ============================ cooperative mega-kernel ============================
// One dispatch for the whole pipeline: the R2 experiment measured ~9-13us per
// dispatch of launch/gap overhead (2 extra dispatches of ~8us modeled work cost
// +26us); 6 dispatches + memset -> 1 dispatch + 5 grid syncs.
__global__ void __launch_bounds__(256, 4) k_mega(MegaArgs a)
{
    cooperative_groups::grid_group grid = cooperative_groups::this_grid();
    const int gsz  = gridDim.x * BS;
    const int gtid = blockIdx.x * BS + threadIdx.x;

    init_phase(a, gtid, gsz);
    grid.sync();
    build_phase(a, gtid, gsz);
    grid.sync();
    gemm_phase<160>(a.xb, a.Wt1, a.as1, a.ad1, a.hb, a.fas, a.fad, a.n);
    grid.sync();
    agg_phase<true, true>(a.hb, a.sn, a.cnt, a.fas, a.fad, a.b1, a.lng, a.lnb, (void*)a.yb, a.n);
    grid.sync();
    gemm_phase<128>(a.yb, a.Wt2, a.as2, a.ad2, a.hb, a.fas, a.fad, a.n);
    grid.sync();
    agg_phase<false, false>(a.hb, a.sn, a.cnt, a.fas, a.fad, a.b2, a.lng, a.lnb, (void*)a.out, a.n);
}

// ============================ fallback wrappers (plain launches) ============================
__global__ void __launch_bounds__(256) kf_init(MegaArgs a) {
    init_phase(a, blockIdx.x * BS + threadIdx.x, gridDim.x * BS);
}
__global__ void __launch_bounds__(256) kf_build(MegaArgs a) {
    build_phase(a, blockIdx.x * BS + threadIdx.x, gridDim.x * BS);
}
__global__ void __launch_bounds__(256) kf_gemm1(MegaArgs a) {
    gemm_phase<160>(a.xb, a.Wt1, a.as1, a.ad1, a.hb, a.fas, a.fad, a.n);
}
__global__ void __launch_bounds__(256) kf_agg1(MegaArgs a) {
    agg_phase<true, true>(a.hb, a.sn, a.cnt, a.fas, a.fad, a.b1, a.lng, a.lnb, (void*)a.yb, a.n);
}
__global__ void __launch_bounds__(256) kf_gemm2(MegaArgs a) {
    gemm_phase<128>(a.yb, a.Wt2, a.as2, a.ad2, a.hb, a.fas, a.fad, a.n);
}
__global__ void __launch_bounds__(256) kf_agg2(MegaArgs a) {
    agg_phase<false, false>(a.hb, a.sn, a.cnt, a.fas, a.fad, a.b2, a.lng, a.lnb, (void*)a.out, a.n);
}

// ============================ launch ============================

extern "C" void kernel_launch(void* const* d_in, const int* in_sizes, int n_in,
                              void* d_out, int out_size, void* d_ws, size_t ws_size,
                              hipStream_t stream) {
    const float* x_base   = (const float*)d_in[0];
    const int*   cell_ids = (const int*)d_in[1];
    const int*   eidx     = (const int*)d_in[2];
    const float* cell_emb = (const float*)d_in[3];
    const float* W1     = (const float*)d_in[4];
    const float* a_src1 = (const float*)d_in[5];
    const float* a_dst1 = (const float*)d_in[6];
    const float* b1     = (const float*)d_in[7];
    const float* ln_g   = (const float*)d_in[8];
    const float* ln_b   = (const float*)d_in[9];
    const float* W2     = (const float*)d_in[10];
    const float* a_src2 = (const float*)d_in[11];
    const float* a_dst2 = (const float*)d_in[12];
    const float* b2     = (const float*)d_in[13];

    const int N = in_sizes[0] / 128;
    const int E = in_sizes[2] / 2;
    const int Npad = ((N + 63) / 64) * 64;

    auto align = [](size_t v) { return (v + 255) & ~(size_t)255; };
    char* p = (char*)d_ws;
    int*   cnt    = (int*)p;   p += align((size_t)N * 4);
    unsigned short* sn = (unsigned short*)p; p += align((size_t)N * STRIDE * 2 + 64);
    _Float16* xb  = (_Float16*)p; p += align((size_t)Npad * 160 * 2);
    _Float16* yb  = (_Float16*)p; p += align((size_t)Npad * 128 * 2);
    _Float16* hb  = (_Float16*)p; p += align((size_t)N * 128 * 2);
    _Float16* Wt1 = (_Float16*)p; p += align((size_t)128 * 160 * 2);
    _Float16* Wt2 = (_Float16*)p; p += align((size_t)128 * 128 * 2);
    float* as_    = (float*)p; p += align((size_t)N * 4);
    float* ad_    = (float*)p; p += align((size_t)N * 4);
    (void)ws_size; (void)n_in; (void)out_size;

    MegaArgs a;
    a.esrc = eidx; a.edst = eidx + E;
    a.cnt = cnt; a.sn = sn;
    a.x = x_base; a.cid = cell_ids; a.emb = cell_emb;
    a.xb = xb;
    a.W1 = W1; a.W2 = W2; a.Wt1 = Wt1; a.Wt2 = Wt2;
    a.as1 = a_src1; a.ad1 = a_dst1; a.b1 = b1;
    a.lng = ln_g; a.lnb = ln_b;
    a.as2 = a_src2; a.ad2 = a_dst2; a.b2 = b2;
    a.yb = yb; a.hb = hb; a.fas = as_; a.fad = ad_;
    a.out = (float*)d_out;
    a.e = E; a.n = N; a.npad = Npad;

    // co-resident grid size (cached across calls)
    static int s_grid = 0;
    if (s_grid == 0) {
        int nb = 0;
        if (hipOccupancyMaxActiveBlocksPerMultiprocessor(&nb, k_mega, BS, 0) != hipSuccess || nb < 1)
            nb = 4;
        int dev = 0, cu = 0;
        hipGetDevice(&dev);
        if (hipDeviceGetAttribute(&cu, hipDeviceAttributeMultiprocessorCount, dev) != hipSuccess || cu < 1)
            cu = 256;
        long g = (long)nb * cu;
        s_grid = (int)(g > 2048 ? 2048 : g);
    }

    void* kargs[] = { (void*)&a };
    hipError_t err = hipLaunchCooperativeKernel((const void*)k_mega, dim3(s_grid), dim3(BS),
                                                kargs, 0, stream);
    if (err != hipSuccess) {
        // fallback: plain 6-dispatch chain (same device code)
        const int nbN = (N + BS - 1) / BS;
        const int nbE = (E + BS - 1) / BS;
        kf_init <<<nbN, BS, 0, stream>>>(a);
        kf_build<<<nbE, BS, 0, stream>>>(a);
        kf_gemm1<<<(N + 31) / 32, BS, 0, stream>>>(a);
        kf_agg1 <<<(N + 3) / 4, BS, 0, stream>>>(a);
        kf_gemm2<<<(N + 31) / 32, BS, 0, stream>>>(a);
        kf_agg2 <<<(N + 3) / 4, BS, 0, stream>>>(a);
    }
}

// Round 5
// 242.112 us; speedup vs baseline: 2.7581x; 2.7581x over previous
//
#include <hip/hip_runtime.h>
#include <hip/hip_fp16.h>
#include <cstdint>
#include <cstddef>

#define NEG_SLOPE 0.2f
#define LN_EPS 1e-5f

constexpr int BS = 256;
constexpr int STRIDE = 96;   // slots per dst node; slot 0 = self-loop (pre-placed, no atomic);
                             // edges append from 1. Poisson(12) in-degree -> max ~40. Mult of 16.

typedef _Float16 f16x8 __attribute__((ext_vector_type(8)));
typedef float f32x4 __attribute__((ext_vector_type(4)));

// ==================== K0: cnt init + self-loop slots + weight transposes ====================
// Replaces the hipMemsetAsync dispatch: cnt=1 reserves slot 0 for the self-loop
// (also saves 50k atomics in K1). Wt1 zero-padded to K=160.
__global__ __launch_bounds__(256) void k_init(
    int* __restrict__ cnt, unsigned short* __restrict__ sn,
    const float* __restrict__ W1, const float* __restrict__ W2,
    _Float16* __restrict__ Wt1, _Float16* __restrict__ Wt2,
    int n, int nbN)
{
    int b = blockIdx.x;
    if (b < nbN) {
        int i = b * BS + threadIdx.x;
        if (i < n) { cnt[i] = 1; sn[(size_t)i * STRIDE] = (unsigned short)i; }
    } else {
        int idx = (b - nbN) * BS + threadIdx.x;
        if (idx < 128 * 160) {
            int nn = idx / 160, k = idx - nn * 160;
            Wt1[idx] = (_Float16)((k < 136) ? W1[(size_t)k * 128 + nn] : 0.f);
        } else if (idx < 128 * 160 + 128 * 128) {
            int j = idx - 128 * 160;
            int nn = j >> 7, k = j & 127;
            Wt2[j] = (_Float16)W2[(size_t)k * 128 + nn];
        }
    }
}

// ==================== K1: edge-atomic scatter (interleaved) + gemm1 ====================
// Even blocks (idx<nbG): gemm1 tile — 4 waves, each 16 rows x 64 cols; A staged
// straight from x_base f32 (f16 cvt on load; no xb buffer). K=136 handled as
// 4x32 from x + one tail iter with emb features (zeros beyond 136 via Wt1 pad).
// Odd blocks + tail: one atomicAdd per edge -> slot in fixed-stride CSR.
// The two roles share no data -> safely concurrent; interleaving keeps the
// atomic fabric and the MFMA/memory pipes busy simultaneously.
__global__ __launch_bounds__(256) void k_scatter_gemm1(
    const int* __restrict__ esrc, const int* __restrict__ edst,
    int* __restrict__ cnt, unsigned short* __restrict__ sn,
    const float* __restrict__ x, const int* __restrict__ cid,
    const float* __restrict__ emb,
    const _Float16* __restrict__ Wt1,
    const float* __restrict__ a_src, const float* __restrict__ a_dst,
    _Float16* __restrict__ hb, float* __restrict__ as_, float* __restrict__ ad_,
    int e, int n, int nbG, int nbA)
{
    __shared__ float red[2][16][2][2];   // [rowgrp][r15][colhalf][vs/vd]
    int b = blockIdx.x;
    int role, idx;
    int nInter = 2 * (nbG < nbA ? nbG : nbA);
    if (b < nInter)      { role = b & 1; idx = b >> 1; }
    else if (nbG < nbA)  { role = 1; idx = (b - nInter) + nbG; }
    else                 { role = 0; idx = (b - nInter) + nbA; }

    if (role == 1) {
        int i = idx * BS + threadIdx.x;
        if (i < e) {
            int s = esrc[i], d = edst[i];
            int slot = atomicAdd(&cnt[d], 1);
            if (slot < STRIDE)                 // safety clamp (unreachable for this data)
                sn[(size_t)d * STRIDE + slot] = (unsigned short)s;
        }
        return;
    }

    // ---- gemm1 tile idx
    int tid = threadIdx.x;
    int wave = tid >> 6, lane = tid & 63;
    int rg = wave >> 1, ch = wave & 1;
    int r15 = lane & 15, q = lane >> 4;
    int rowBase = idx * 32 + rg * 16;
    int colBase = ch * 64;
    int row = rowBase + r15;
    bool ok = row < n;
    int rl = ok ? row : n - 1;                 // clamped load row (no OOB reads)

    f32x4 acc[4] = {};
    const _Float16* Wp[4];
    #pragma unroll
    for (int s = 0; s < 4; ++s)
        Wp[s] = Wt1 + (size_t)(colBase + s * 16 + r15) * 160 + q * 8;
    const float* Xp = x + (size_t)rl * 128 + q * 8;

    #pragma unroll
    for (int k0 = 0; k0 < 128; k0 += 32) {
        f16x8 wv[4];
        #pragma unroll
        for (int s = 0; s < 4; ++s) wv[s] = *(const f16x8*)(Wp[s] + k0);
        float4 xlo = *(const float4*)(Xp + k0);
        float4 xhi = *(const float4*)(Xp + k0 + 4);
        f16x8 xv;
        xv[0] = (_Float16)xlo.x; xv[1] = (_Float16)xlo.y;
        xv[2] = (_Float16)xlo.z; xv[3] = (_Float16)xlo.w;
        xv[4] = (_Float16)xhi.x; xv[5] = (_Float16)xhi.y;
        xv[6] = (_Float16)xhi.z; xv[7] = (_Float16)xhi.w;
        #pragma unroll
        for (int s = 0; s < 4; ++s)
            acc[s] = __builtin_amdgcn_mfma_f32_16x16x32_f16(wv[s], xv, acc[s], 0, 0, 0);
    }
    {   // tail k0=128: k=128..135 are emb features (q==0 lanes); 136..159 zero (Wt1 padded)
        f16x8 wv[4];
        #pragma unroll
        for (int s = 0; s < 4; ++s) wv[s] = *(const f16x8*)(Wp[s] + 128);
        f16x8 xv;
        #pragma unroll
        for (int j = 0; j < 8; ++j) xv[j] = (_Float16)0.f;
        if (q == 0) {
            const float* er = emb + (size_t)cid[rl] * 8;
            float4 e0 = *(const float4*)er;
            float4 e1 = *(const float4*)(er + 4);
            xv[0] = (_Float16)e0.x; xv[1] = (_Float16)e0.y;
            xv[2] = (_Float16)e0.z; xv[3] = (_Float16)e0.w;
            xv[4] = (_Float16)e1.x; xv[5] = (_Float16)e1.y;
            xv[6] = (_Float16)e1.z; xv[7] = (_Float16)e1.w;
        }
        #pragma unroll
        for (int s = 0; s < 4; ++s)
            acc[s] = __builtin_amdgcn_mfma_f32_16x16x32_f16(wv[s], xv, acc[s], 0, 0, 0);
    }

    float vs = 0.f, vd = 0.f;
    #pragma unroll
    for (int s = 0; s < 4; ++s) {
        float4 as4 = *(const float4*)&a_src[colBase + s * 16 + q * 4];
        float4 ad4 = *(const float4*)&a_dst[colBase + s * 16 + q * 4];
        f32x4 d = acc[s];
        vs += d[0]*as4.x + d[1]*as4.y + d[2]*as4.z + d[3]*as4.w;
        vd += d[0]*ad4.x + d[1]*ad4.y + d[2]*ad4.z + d[3]*ad4.w;
        if (ok) {
            ushort4 u;
            u.x = __half_as_ushort(__float2half_rn(d[0]));
            u.y = __half_as_ushort(__float2half_rn(d[1]));
            u.z = __half_as_ushort(__float2half_rn(d[2]));
            u.w = __half_as_ushort(__float2half_rn(d[3]));
            *(ushort4*)&hb[(size_t)row * 128 + colBase + s * 16 + q * 4] = u;
        }
    }
    vs += __shfl_xor(vs, 16); vs += __shfl_xor(vs, 32);
    vd += __shfl_xor(vd, 16); vd += __shfl_xor(vd, 32);
    if (q == 0) { red[rg][r15][ch][0] = vs; red[rg][r15][ch][1] = vd; }
    __syncthreads();
    if (ch == 0 && q == 0 && ok) {
        as_[row] = red[rg][r15][0][0] + red[rg][r15][1][0];
        ad_[row] = red[rg][r15][0][1] + red[rg][r15][1][1];
    }
}

// ==================== K2: agg layer1 + LN + ELU + gemm2 (fused per 32-row tile) ===========
// gemm2's A-tile (rows 32t..32t+32 of layer-1 output) is exactly this block's
// 32 agg results -> meet in LDS, no yb global round-trip. agg reads GLOBAL h1/
// as1/ad1 (complete at the K1 boundary); gemm2 reads only LOCAL agg output.
// yt padded to 144 halves/row (288B: 16B-aligned rows, banks spread).
__global__ __launch_bounds__(256) void k_agg1_gemm2(
    const _Float16* __restrict__ h1, const unsigned short* __restrict__ sn,
    const int* __restrict__ cnt, const float* __restrict__ as1,
    const float* __restrict__ ad1, const float* __restrict__ b1,
    const float* __restrict__ lng, const float* __restrict__ lnb,
    const _Float16* __restrict__ Wt2,
    const float* __restrict__ a_src2, const float* __restrict__ a_dst2,
    _Float16* __restrict__ h2, float* __restrict__ as2, float* __restrict__ ad2,
    int nn)
{
    __shared__ _Float16 yt[32][144];
    __shared__ float red[2][16][2][2];
    int t = blockIdx.x;
    int tid = threadIdx.x;
    int wave = tid >> 6, lane = tid & 63;
    int l4 = lane & 15, q = lane >> 4;
    const char* hbB = (const char*)h1;

    // ---- agg1: each wave handles 8 consecutive nodes of this block's 32
    for (int i = 0; i < 8; ++i) {
        int node = t * 32 + wave * 8 + i;
        if (node >= nn) break;                         // wave-uniform
        int len = cnt[node];
        len = len < STRIDE ? len : STRIDE;
        len = __builtin_amdgcn_readfirstlane(len);
        int start = node * STRIDE;
        float adv = ad1[node];

        float acc[8] = {0.f, 0.f, 0.f, 0.f, 0.f, 0.f, 0.f, 0.f};
        float dsum = 0.f;
        for (int j = 0; j < len; j += 16) {
            int rem = len - j;                          // uniform
            int offB = (l4 < rem) ? ((int)sn[start + j + l4] << 8) : 0;
            float tt = as1[offB >> 8] + adv;            // inline edge weight
            tt = tt > 0.f ? tt : NEG_SLOPE * tt;
            float w0 = __expf(fminf(tt, 70.f));
            #pragma unroll
            for (int v = 0; v < 4; ++v) {
                int e = 4 * v + q;
                int ob  = __shfl(offB, e);
                float w = __shfl(w0, e);
                if (e < rem) {                          // quarter-uniform: skip dead gathers
                    f16x8 hv = *(const f16x8*)(hbB + ob + l4 * 16);
                    #pragma unroll
                    for (int c = 0; c < 8; ++c)
                        acc[c] = fmaf(w, (float)hv[c], acc[c]);
                    dsum += w;
                }
            }
        }
        #pragma unroll
        for (int c = 0; c < 8; ++c) {
            acc[c] += __shfl_xor(acc[c], 16);
            acc[c] += __shfl_xor(acc[c], 32);
        }
        dsum += __shfl_xor(dsum, 16);
        dsum += __shfl_xor(dsum, 32);

        float inv = 1.f / dsum;
        float4 b0 = *(const float4*)&b1[l4 * 8];
        float4 bb = *(const float4*)&b1[l4 * 8 + 4];
        float vv[8];
        vv[0] = acc[0] * inv + b0.x; vv[1] = acc[1] * inv + b0.y;
        vv[2] = acc[2] * inv + b0.z; vv[3] = acc[3] * inv + b0.w;
        vv[4] = acc[4] * inv + bb.x; vv[5] = acc[5] * inv + bb.y;
        vv[6] = acc[6] * inv + bb.z; vv[7] = acc[7] * inv + bb.w;

        // LayerNorm + ELU
        float s1 = 0.f, s2 = 0.f;
        #pragma unroll
        for (int c = 0; c < 8; ++c) { s1 += vv[c]; s2 += vv[c] * vv[c]; }
        #pragma unroll
        for (int o = 1; o < 16; o <<= 1) {
            s1 += __shfl_xor(s1, o);
            s2 += __shfl_xor(s2, o);
        }
        float mean = s1 * (1.f / 128.f);
        float var  = s2 * (1.f / 128.f) - mean * mean;
        float r = rsqrtf(var + LN_EPS);
        float4 g0 = *(const float4*)&lng[l4 * 8];
        float4 g1 = *(const float4*)&lng[l4 * 8 + 4];
        float4 p0 = *(const float4*)&lnb[l4 * 8];
        float4 p1 = *(const float4*)&lnb[l4 * 8 + 4];
        float gg[8] = {g0.x, g0.y, g0.z, g0.w, g1.x, g1.y, g1.z, g1.w};
        float pp[8] = {p0.x, p0.y, p0.z, p0.w, p1.x, p1.y, p1.z, p1.w};
        #pragma unroll
        for (int c = 0; c < 8; ++c) {
            float u = (vv[c] - mean) * r * gg[c] + pp[c];
            vv[c] = u > 0.f ? u : __expf(u) - 1.f;       // ELU
        }

        if (q == 0) {
            f16x8 o;
            #pragma unroll
            for (int c = 0; c < 8; ++c) o[c] = (_Float16)vv[c];
            *(f16x8*)&yt[wave * 8 + i][l4 * 8] = o;
        }
    }
    __syncthreads();

    // ---- gemm2 (K=128) from the LDS tile
    int rg = wave >> 1, ch = wave & 1;
    int r15 = lane & 15;
    int rowBase = t * 32 + rg * 16;
    int colBase = ch * 64;
    int row = rowBase + r15;
    bool ok = row < nn;

    f32x4 acc2[4] = {};
    const _Float16* Wp[4];
    #pragma unroll
    for (int s = 0; s < 4; ++s)
        Wp[s] = Wt2 + (size_t)(colBase + s * 16 + r15) * 128 + q * 8;
    const _Float16* Yp = &yt[rg * 16 + r15][q * 8];

    #pragma unroll
    for (int k0 = 0; k0 < 128; k0 += 32) {
        f16x8 wv[4];
        #pragma unroll
        for (int s = 0; s < 4; ++s) wv[s] = *(const f16x8*)(Wp[s] + k0);
        f16x8 xv = *(const f16x8*)(Yp + k0);
        #pragma unroll
        for (int s = 0; s < 4; ++s)
            acc2[s] = __builtin_amdgcn_mfma_f32_16x16x32_f16(wv[s], xv, acc2[s], 0, 0, 0);
    }

    float vs = 0.f, vd = 0.f;
    #pragma unroll
    for (int s = 0; s < 4; ++s) {
        float4 as4 = *(const float4*)&a_src2[colBase + s * 16 + q * 4];
        float4 ad4 = *(const float4*)&a_dst2[colBase + s * 16 + q * 4];
        f32x4 d = acc2[s];
        vs += d[0]*as4.x + d[1]*as4.y + d[2]*as4.z + d[3]*as4.w;
        vd += d[0]*ad4.x + d[1]*ad4.y + d[2]*ad4.z + d[3]*ad4.w;
        if (ok) {
            ushort4 u;
            u.x = __half_as_ushort(__float2half_rn(d[0]));
            u.y = __half_as_ushort(__float2half_rn(d[1]));
            u.z = __half_as_ushort(__float2half_rn(d[2]));
            u.w = __half_as_ushort(__float2half_rn(d[3]));
            *(ushort4*)&h2[(size_t)row * 128 + colBase + s * 16 + q * 4] = u;
        }
    }
    vs += __shfl_xor(vs, 16); vs += __shfl_xor(vs, 32);
    vd += __shfl_xor(vd, 16); vd += __shfl_xor(vd, 32);
    if (q == 0) { red[rg][r15][ch][0] = vs; red[rg][r15][ch][1] = vd; }
    __syncthreads();
    if (ch == 0 && q == 0 && ok) {
        as2[row] = red[rg][r15][0][0] + red[rg][r15][1][0];
        ad2[row] = red[rg][r15][0][1] + red[rg][r15][1][1];
    }
}

// ==================== K3: agg layer2 (final, fp32 out) ====================
__global__ __launch_bounds__(256) void k_agg2(
    const _Float16* __restrict__ hb, const unsigned short* __restrict__ sn,
    const int* __restrict__ cnt, const float* __restrict__ as_,
    const float* __restrict__ ad_, const float* __restrict__ bias,
    float* __restrict__ out, int n_nodes)
{
    int wave = threadIdx.x >> 6, lane = threadIdx.x & 63;
    int n = blockIdx.x * 4 + wave;
    if (n >= n_nodes) return;
    int len = cnt[n];
    len = len < STRIDE ? len : STRIDE;
    len = __builtin_amdgcn_readfirstlane(len);
    int start = n * STRIDE;
    int l4 = lane & 15, q = lane >> 4;
    float adv = ad_[n];
    const char* hbB = (const char*)hb;

    float acc[8] = {0.f, 0.f, 0.f, 0.f, 0.f, 0.f, 0.f, 0.f};
    float dsum = 0.f;
    for (int j = 0; j < len; j += 16) {
        int rem = len - j;
        int offB = (l4 < rem) ? ((int)sn[start + j + l4] << 8) : 0;
        float t = as_[offB >> 8] + adv;
        t = t > 0.f ? t : NEG_SLOPE * t;
        float w0 = __expf(fminf(t, 70.f));
        #pragma unroll
        for (int v = 0; v < 4; ++v) {
            int e = 4 * v + q;
            int ob  = __shfl(offB, e);
            float w = __shfl(w0, e);
            if (e < rem) {
                f16x8 hv = *(const f16x8*)(hbB + ob + l4 * 16);
                #pragma unroll
                for (int c = 0; c < 8; ++c)
                    acc[c] = fmaf(w, (float)hv[c], acc[c]);
                dsum += w;
            }
        }
    }
    #pragma unroll
    for (int c = 0; c < 8; ++c) {
        acc[c] += __shfl_xor(acc[c], 16);
        acc[c] += __shfl_xor(acc[c], 32);
    }
    dsum += __shfl_xor(dsum, 16);
    dsum += __shfl_xor(dsum, 32);

    if (q == 0) {
        float inv = 1.f / dsum;
        float4 b0 = *(const float4*)&bias[l4 * 8];
        float4 b1 = *(const float4*)&bias[l4 * 8 + 4];
        float4 o0 = make_float4(acc[0]*inv + b0.x, acc[1]*inv + b0.y,
                                acc[2]*inv + b0.z, acc[3]*inv + b0.w);
        float4 o1 = make_float4(acc[4]*inv + b1.x, acc[5]*inv + b1.y,
                                acc[6]*inv + b1.z, acc[7]*inv + b1.w);
        *(float4*)(out + (size_t)n * 128 + l4 * 8)     = o0;
        *(float4*)(out + (size_t)n * 128 + l4 * 8 + 4) = o1;
    }
}

// ============================ launch ============================

extern "C" void kernel_launch(void* const* d_in, const int* in_sizes, int n_in,
                              void* d_out, int out_size, void* d_ws, size_t ws_size,
                              hipStream_t stream) {
    const float* x_base   = (const float*)d_in[0];
    const int*   cell_ids = (const int*)d_in[1];
    const int*   eidx     = (const int*)d_in[2];
    const float* cell_emb = (const float*)d_in[3];
    const float* W1     = (const float*)d_in[4];
    const float* a_src1 = (const float*)d_in[5];
    const float* a_dst1 = (const float*)d_in[6];
    const float* b1     = (const float*)d_in[7];
    const float* ln_g   = (const float*)d_in[8];
    const float* ln_b   = (const float*)d_in[9];
    const float* W2     = (const float*)d_in[10];
    const float* a_src2 = (const float*)d_in[11];
    const float* a_dst2 = (const float*)d_in[12];
    const float* b2     = (const float*)d_in[13];

    const int N = in_sizes[0] / 128;
    const int E = in_sizes[2] / 2;

    const int* esrc = eidx;
    const int* edst = eidx + E;

    auto align = [](size_t v) { return (v + 255) & ~(size_t)255; };
    char* p = (char*)d_ws;
    int*   cnt    = (int*)p;   p += align((size_t)N * 4);
    unsigned short* sn = (unsigned short*)p; p += align((size_t)N * STRIDE * 2 + 64);
    _Float16* h1  = (_Float16*)p; p += align((size_t)N * 128 * 2);
    _Float16* h2  = (_Float16*)p; p += align((size_t)N * 128 * 2);
    _Float16* Wt1 = (_Float16*)p; p += align((size_t)128 * 160 * 2);
    _Float16* Wt2 = (_Float16*)p; p += align((size_t)128 * 128 * 2);
    float* as1    = (float*)p; p += align((size_t)N * 4);
    float* ad1    = (float*)p; p += align((size_t)N * 4);
    float* as2    = (float*)p; p += align((size_t)N * 4);
    float* ad2    = (float*)p; p += align((size_t)N * 4);
    (void)ws_size; (void)n_in; (void)out_size;

    const int nbN = (N + BS - 1) / BS;
    const int nbA = (E + BS - 1) / BS;                 // edge-atomic blocks
    const int nbG = (N + 31) / 32;                     // gemm tiles (32 rows each)
    const int wblocks = (128 * 160 + 128 * 128 + BS - 1) / BS;

    k_init<<<nbN + wblocks, BS, 0, stream>>>(cnt, sn, W1, W2, Wt1, Wt2, N, nbN);
    k_scatter_gemm1<<<nbG + nbA, BS, 0, stream>>>(
        esrc, edst, cnt, sn, x_base, cell_ids, cell_emb, Wt1,
        a_src1, a_dst1, h1, as1, ad1, E, N, nbG, nbA);
    k_agg1_gemm2<<<nbG, BS, 0, stream>>>(
        h1, sn, cnt, as1, ad1, b1, ln_g, ln_b, Wt2,
        a_src2, a_dst2, h2, as2, ad2, N);
    k_agg2<<<(N + 3) / 4, BS, 0, stream>>>(
        h2, sn, cnt, as2, ad2, b2, (float*)d_out, N);
}

// Round 6
// 221.020 us; speedup vs baseline: 3.0213x; 1.0954x over previous
//
#include <hip/hip_runtime.h>
#include <hip/hip_fp16.h>
#include <cstdint>
#include <cstddef>

#define NEG_SLOPE 0.2f
#define LN_EPS 1e-5f

constexpr int BS = 256;
constexpr int STRIDE = 96;   // slots per dst node; slot 0 = self-loop (pre-placed, no atomic);
                             // edges append from 1. Poisson(12) in-degree -> max ~40. Mult of 16.

typedef _Float16 f16x8 __attribute__((ext_vector_type(8)));
typedef float f32x4 __attribute__((ext_vector_type(4)));

// ==================== K0: cnt init + self-loop slots + weight transposes ====================
__global__ __launch_bounds__(256) void k_init(
    int* __restrict__ cnt, unsigned short* __restrict__ sn,
    const float* __restrict__ W1, const float* __restrict__ W2,
    _Float16* __restrict__ Wt1, _Float16* __restrict__ Wt2,
    int n, int nbN)
{
    int b = blockIdx.x;
    if (b < nbN) {
        int i = b * BS + threadIdx.x;
        if (i < n) { cnt[i] = 1; sn[(size_t)i * STRIDE] = (unsigned short)i; }
    } else {
        int idx = (b - nbN) * BS + threadIdx.x;
        if (idx < 128 * 160) {
            int nn = idx / 160, k = idx - nn * 160;
            Wt1[idx] = (_Float16)((k < 136) ? W1[(size_t)k * 128 + nn] : 0.f);
        } else if (idx < 128 * 160 + 128 * 128) {
            int j = idx - 128 * 160;
            int nn = j >> 7, k = j & 127;
            Wt2[j] = (_Float16)W2[(size_t)k * 128 + nn];
        }
    }
}

// ==================== K1: edge-atomic scatter (interleaved) + gemm1 ====================
// (unchanged from R5 — kept identical for clean attribution of the agg restructure)
__global__ __launch_bounds__(256) void k_scatter_gemm1(
    const int* __restrict__ esrc, const int* __restrict__ edst,
    int* __restrict__ cnt, unsigned short* __restrict__ sn,
    const float* __restrict__ x, const int* __restrict__ cid,
    const float* __restrict__ emb,
    const _Float16* __restrict__ Wt1,
    const float* __restrict__ a_src, const float* __restrict__ a_dst,
    _Float16* __restrict__ hb, float* __restrict__ as_, float* __restrict__ ad_,
    int e, int n, int nbG, int nbA)
{
    __shared__ float red[2][16][2][2];   // [rowgrp][r15][colhalf][vs/vd]
    int b = blockIdx.x;
    int role, idx;
    int nInter = 2 * (nbG < nbA ? nbG : nbA);
    if (b < nInter)      { role = b & 1; idx = b >> 1; }
    else if (nbG < nbA)  { role = 1; idx = (b - nInter) + nbG; }
    else                 { role = 0; idx = (b - nInter) + nbA; }

    if (role == 1) {
        int i = idx * BS + threadIdx.x;
        if (i < e) {
            int s = esrc[i], d = edst[i];
            int slot = atomicAdd(&cnt[d], 1);
            if (slot < STRIDE)                 // safety clamp (unreachable for this data)
                sn[(size_t)d * STRIDE + slot] = (unsigned short)s;
        }
        return;
    }

    // ---- gemm1 tile idx
    int tid = threadIdx.x;
    int wave = tid >> 6, lane = tid & 63;
    int rg = wave >> 1, ch = wave & 1;
    int r15 = lane & 15, q = lane >> 4;
    int rowBase = idx * 32 + rg * 16;
    int colBase = ch * 64;
    int row = rowBase + r15;
    bool ok = row < n;
    int rl = ok ? row : n - 1;                 // clamped load row (no OOB reads)

    f32x4 acc[4] = {};
    const _Float16* Wp[4];
    #pragma unroll
    for (int s = 0; s < 4; ++s)
        Wp[s] = Wt1 + (size_t)(colBase + s * 16 + r15) * 160 + q * 8;
    const float* Xp = x + (size_t)rl * 128 + q * 8;

    #pragma unroll
    for (int k0 = 0; k0 < 128; k0 += 32) {
        f16x8 wv[4];
        #pragma unroll
        for (int s = 0; s < 4; ++s) wv[s] = *(const f16x8*)(Wp[s] + k0);
        float4 xlo = *(const float4*)(Xp + k0);
        float4 xhi = *(const float4*)(Xp + k0 + 4);
        f16x8 xv;
        xv[0] = (_Float16)xlo.x; xv[1] = (_Float16)xlo.y;
        xv[2] = (_Float16)xlo.z; xv[3] = (_Float16)xlo.w;
        xv[4] = (_Float16)xhi.x; xv[5] = (_Float16)xhi.y;
        xv[6] = (_Float16)xhi.z; xv[7] = (_Float16)xhi.w;
        #pragma unroll
        for (int s = 0; s < 4; ++s)
            acc[s] = __builtin_amdgcn_mfma_f32_16x16x32_f16(wv[s], xv, acc[s], 0, 0, 0);
    }
    {   // tail k0=128: k=128..135 are emb features (q==0 lanes); 136..159 zero (Wt1 padded)
        f16x8 wv[4];
        #pragma unroll
        for (int s = 0; s < 4; ++s) wv[s] = *(const f16x8*)(Wp[s] + 128);
        f16x8 xv;
        #pragma unroll
        for (int j = 0; j < 8; ++j) xv[j] = (_Float16)0.f;
        if (q == 0) {
            const float* er = emb + (size_t)cid[rl] * 8;
            float4 e0 = *(const float4*)er;
            float4 e1 = *(const float4*)(er + 4);
            xv[0] = (_Float16)e0.x; xv[1] = (_Float16)e0.y;
            xv[2] = (_Float16)e0.z; xv[3] = (_Float16)e0.w;
            xv[4] = (_Float16)e1.x; xv[5] = (_Float16)e1.y;
            xv[6] = (_Float16)e1.z; xv[7] = (_Float16)e1.w;
        }
        #pragma unroll
        for (int s = 0; s < 4; ++s)
            acc[s] = __builtin_amdgcn_mfma_f32_16x16x32_f16(wv[s], xv, acc[s], 0, 0, 0);
    }

    float vs = 0.f, vd = 0.f;
    #pragma unroll
    for (int s = 0; s < 4; ++s) {
        float4 as4 = *(const float4*)&a_src[colBase + s * 16 + q * 4];
        float4 ad4 = *(const float4*)&a_dst[colBase + s * 16 + q * 4];
        f32x4 d = acc[s];
        vs += d[0]*as4.x + d[1]*as4.y + d[2]*as4.z + d[3]*as4.w;
        vd += d[0]*ad4.x + d[1]*ad4.y + d[2]*ad4.z + d[3]*ad4.w;
        if (ok) {
            ushort4 u;
            u.x = __half_as_ushort(__float2half_rn(d[0]));
            u.y = __half_as_ushort(__float2half_rn(d[1]));
            u.z = __half_as_ushort(__float2half_rn(d[2]));
            u.w = __half_as_ushort(__float2half_rn(d[3]));
            *(ushort4*)&hb[(size_t)row * 128 + colBase + s * 16 + q * 4] = u;
        }
    }
    vs += __shfl_xor(vs, 16); vs += __shfl_xor(vs, 32);
    vd += __shfl_xor(vd, 16); vd += __shfl_xor(vd, 32);
    if (q == 0) { red[rg][r15][ch][0] = vs; red[rg][r15][ch][1] = vd; }
    __syncthreads();
    if (ch == 0 && q == 0 && ok) {
        as_[row] = red[rg][r15][0][0] + red[rg][r15][1][0];
        ad_[row] = red[rg][r15][0][1] + red[rg][r15][1][1];
    }
}

// ==================== K2: agg layer1 (quarter-per-node) + LN + ELU + gemm2 ====================
// Latency fix: a node's 128 ch = 16 lanes x 8 ch = ONE quarter-wave. Each quarter
// owns its own node -> 4 independent gather chains per wave (was 1), no serial
// 8-node loop (512 threads = 32 quarters = the whole 32-row tile), and the
// acc/dsum cross-lane reduces vanish (each lane sums ALL its node's edges).
// Edges in chunks of 4 via one 8B broadcast sn load; lane l4 computes the exp
// for edge j+(l4&3) -> one exp wave-inst still covers 16 edges. LN reduces are
// quarter-internal (shfl_xor o=1..8). gemm2: 8 waves, each 16 rows x 32 cols.
__global__ __launch_bounds__(512, 8) void k_agg1_gemm2(
    const _Float16* __restrict__ h1, const unsigned short* __restrict__ sn,
    const int* __restrict__ cnt, const float* __restrict__ as1,
    const float* __restrict__ ad1, const float* __restrict__ b1,
    const float* __restrict__ lng, const float* __restrict__ lnb,
    const _Float16* __restrict__ Wt2,
    const float* __restrict__ a_src2, const float* __restrict__ a_dst2,
    _Float16* __restrict__ h2, float* __restrict__ as2, float* __restrict__ ad2,
    int nn)
{
    __shared__ _Float16 yt[32][144];
    __shared__ float red[2][16][4][2];
    int t = blockIdx.x;
    int tid = threadIdx.x;
    int wave = tid >> 6, lane = tid & 63;
    int l4 = lane & 15, q = lane >> 4;
    int qg = wave * 4 + q;                     // 0..31: this quarter's node slot in the tile
    int node = t * 32 + qg;
    bool valid = node < nn;
    const char* hbB = (const char*)h1;

    int len = 0; float adv = 0.f;
    if (valid) {
        len = cnt[node];
        len = len < STRIDE ? len : STRIDE;
        adv = ad1[node];
    }
    int start = node * STRIDE;
    int sub = l4 & 3;

    float acc[8] = {0.f, 0.f, 0.f, 0.f, 0.f, 0.f, 0.f, 0.f};
    float dsum = 0.f;
    for (int j = 0; j < len; j += 4) {
        int rem = len - j;                      // quarter-uniform
        unsigned long long s4 = *(const unsigned long long*)(sn + start + j);  // 4 src ids, broadcast
        int my = (int)((s4 >> (sub * 16)) & 0xFFFFull);
        float tt = as1[my] + adv;               // this lane's edge weight (edge j+sub)
        tt = tt > 0.f ? tt : NEG_SLOPE * tt;
        float w = __expf(fminf(tt, 70.f));
        #pragma unroll
        for (int i = 0; i < 4; ++i) {
            if (i < rem) {                      // quarter-uniform mask: skip dead gathers
                int si = (int)((s4 >> (i * 16)) & 0xFFFFull);
                float wi = __shfl(w, (lane & 48) | i);
                f16x8 hv = *(const f16x8*)(hbB + ((size_t)si << 8) + l4 * 16);
                #pragma unroll
                for (int c = 0; c < 8; ++c)
                    acc[c] = fmaf(wi, (float)hv[c], acc[c]);
                dsum += wi;
            }
        }
    }

    if (valid) {
        float inv = 1.f / dsum;                 // dsum identical across the quarter's 16 lanes
        float4 b0 = *(const float4*)&b1[l4 * 8];
        float4 bb = *(const float4*)&b1[l4 * 8 + 4];
        float vv[8];
        vv[0] = acc[0] * inv + b0.x; vv[1] = acc[1] * inv + b0.y;
        vv[2] = acc[2] * inv + b0.z; vv[3] = acc[3] * inv + b0.w;
        vv[4] = acc[4] * inv + bb.x; vv[5] = acc[5] * inv + bb.y;
        vv[6] = acc[6] * inv + bb.z; vv[7] = acc[7] * inv + bb.w;

        // LayerNorm across the quarter's 16 lanes (o=1..8 stay within the quarter)
        float s1 = 0.f, s2 = 0.f;
        #pragma unroll
        for (int c = 0; c < 8; ++c) { s1 += vv[c]; s2 += vv[c] * vv[c]; }
        #pragma unroll
        for (int o = 1; o < 16; o <<= 1) {
            s1 += __shfl_xor(s1, o);
            s2 += __shfl_xor(s2, o);
        }
        float mean = s1 * (1.f / 128.f);
        float var  = s2 * (1.f / 128.f) - mean * mean;
        float r = rsqrtf(var + LN_EPS);
        float4 g0 = *(const float4*)&lng[l4 * 8];
        float4 g1 = *(const float4*)&lng[l4 * 8 + 4];
        float4 p0 = *(const float4*)&lnb[l4 * 8];
        float4 p1 = *(const float4*)&lnb[l4 * 8 + 4];
        float gg[8] = {g0.x, g0.y, g0.z, g0.w, g1.x, g1.y, g1.z, g1.w};
        float pp[8] = {p0.x, p0.y, p0.z, p0.w, p1.x, p1.y, p1.z, p1.w};
        f16x8 o;
        #pragma unroll
        for (int c = 0; c < 8; ++c) {
            float u = (vv[c] - mean) * r * gg[c] + pp[c];
            u = u > 0.f ? u : __expf(u) - 1.f;   // ELU
            o[c] = (_Float16)u;
        }
        *(f16x8*)&yt[qg][l4 * 8] = o;
    } else {
        f16x8 z;
        #pragma unroll
        for (int c = 0; c < 8; ++c) z[c] = (_Float16)0.f;
        *(f16x8*)&yt[qg][l4 * 8] = z;
    }
    __syncthreads();

    // ---- gemm2 (K=128) from the LDS tile: 8 waves = 2 rowgroups x 4 col-chunks
    int rg = wave >> 2, cc = wave & 3;
    int r15 = l4;
    int row = t * 32 + rg * 16 + r15;
    bool ok = row < nn;

    f32x4 acc2[2] = {};
    const _Float16* Wp[2];
    #pragma unroll
    for (int s = 0; s < 2; ++s)
        Wp[s] = Wt2 + (size_t)(cc * 32 + s * 16 + r15) * 128 + q * 8;
    const _Float16* Yp = &yt[rg * 16 + r15][q * 8];

    #pragma unroll
    for (int k0 = 0; k0 < 128; k0 += 32) {
        f16x8 wv[2];
        #pragma unroll
        for (int s = 0; s < 2; ++s) wv[s] = *(const f16x8*)(Wp[s] + k0);
        f16x8 xv = *(const f16x8*)(Yp + k0);
        #pragma unroll
        for (int s = 0; s < 2; ++s)
            acc2[s] = __builtin_amdgcn_mfma_f32_16x16x32_f16(wv[s], xv, acc2[s], 0, 0, 0);
    }

    float vs = 0.f, vd = 0.f;
    #pragma unroll
    for (int s = 0; s < 2; ++s) {
        float4 as4 = *(const float4*)&a_src2[cc * 32 + s * 16 + q * 4];
        float4 ad4 = *(const float4*)&a_dst2[cc * 32 + s * 16 + q * 4];
        f32x4 d = acc2[s];
        vs += d[0]*as4.x + d[1]*as4.y + d[2]*as4.z + d[3]*as4.w;
        vd += d[0]*ad4.x + d[1]*ad4.y + d[2]*ad4.z + d[3]*ad4.w;
        if (ok) {
            ushort4 u;
            u.x = __half_as_ushort(__float2half_rn(d[0]));
            u.y = __half_as_ushort(__float2half_rn(d[1]));
            u.z = __half_as_ushort(__float2half_rn(d[2]));
            u.w = __half_as_ushort(__float2half_rn(d[3]));
            *(ushort4*)&h2[(size_t)row * 128 + cc * 32 + s * 16 + q * 4] = u;
        }
    }
    vs += __shfl_xor(vs, 16); vs += __shfl_xor(vs, 32);
    vd += __shfl_xor(vd, 16); vd += __shfl_xor(vd, 32);
    if (q == 0) { red[rg][r15][cc][0] = vs; red[rg][r15][cc][1] = vd; }
    __syncthreads();
    if (cc == 0 && q == 0 && ok) {
        as2[row] = red[rg][r15][0][0] + red[rg][r15][1][0]
                 + red[rg][r15][2][0] + red[rg][r15][3][0];
        ad2[row] = red[rg][r15][0][1] + red[rg][r15][1][1]
                 + red[rg][r15][2][1] + red[rg][r15][3][1];
    }
}

// ==================== K3: agg layer2 (quarter-per-node, fp32 out) ====================
__global__ __launch_bounds__(256) void k_agg2(
    const _Float16* __restrict__ hb, const unsigned short* __restrict__ sn,
    const int* __restrict__ cnt, const float* __restrict__ as_,
    const float* __restrict__ ad_, const float* __restrict__ bias,
    float* __restrict__ out, int n_nodes)
{
    int tid = threadIdx.x;
    int wave = tid >> 6, lane = tid & 63;
    int l4 = lane & 15, q = lane >> 4;
    int node = blockIdx.x * 16 + wave * 4 + q;
    if (node >= n_nodes) return;
    int len = cnt[node];
    len = len < STRIDE ? len : STRIDE;
    int start = node * STRIDE;
    int sub = l4 & 3;
    float adv = ad_[node];
    const char* hbB = (const char*)hb;

    float acc[8] = {0.f, 0.f, 0.f, 0.f, 0.f, 0.f, 0.f, 0.f};
    float dsum = 0.f;
    for (int j = 0; j < len; j += 4) {
        int rem = len - j;
        unsigned long long s4 = *(const unsigned long long*)(sn + start + j);
        int my = (int)((s4 >> (sub * 16)) & 0xFFFFull);
        float t = as_[my] + adv;
        t = t > 0.f ? t : NEG_SLOPE * t;
        float w = __expf(fminf(t, 70.f));
        #pragma unroll
        for (int i = 0; i < 4; ++i) {
            if (i < rem) {
                int si = (int)((s4 >> (i * 16)) & 0xFFFFull);
                float wi = __shfl(w, (lane & 48) | i);
                f16x8 hv = *(const f16x8*)(hbB + ((size_t)si << 8) + l4 * 16);
                #pragma unroll
                for (int c = 0; c < 8; ++c)
                    acc[c] = fmaf(wi, (float)hv[c], acc[c]);
                dsum += wi;
            }
        }
    }

    float inv = 1.f / dsum;
    float4 b0 = *(const float4*)&bias[l4 * 8];
    float4 b1 = *(const float4*)&bias[l4 * 8 + 4];
    float4 o0 = make_float4(acc[0]*inv + b0.x, acc[1]*inv + b0.y,
                            acc[2]*inv + b0.z, acc[3]*inv + b0.w);
    float4 o1 = make_float4(acc[4]*inv + b1.x, acc[5]*inv + b1.y,
                            acc[6]*inv + b1.z, acc[7]*inv + b1.w);
    *(float4*)(out + (size_t)node * 128 + l4 * 8)     = o0;
    *(float4*)(out + (size_t)node * 128 + l4 * 8 + 4) = o1;
}

// ============================ launch ============================

extern "C" void kernel_launch(void* const* d_in, const int* in_sizes, int n_in,
                              void* d_out, int out_size, void* d_ws, size_t ws_size,
                              hipStream_t stream) {
    const float* x_base   = (const float*)d_in[0];
    const int*   cell_ids = (const int*)d_in[1];
    const int*   eidx     = (const int*)d_in[2];
    const float* cell_emb = (const float*)d_in[3];
    const float* W1     = (const float*)d_in[4];
    const float* a_src1 = (const float*)d_in[5];
    const float* a_dst1 = (const float*)d_in[6];
    const float* b1     = (const float*)d_in[7];
    const float* ln_g   = (const float*)d_in[8];
    const float* ln_b   = (const float*)d_in[9];
    const float* W2     = (const float*)d_in[10];
    const float* a_src2 = (const float*)d_in[11];
    const float* a_dst2 = (const float*)d_in[12];
    const float* b2     = (const float*)d_in[13];

    const int N = in_sizes[0] / 128;
    const int E = in_sizes[2] / 2;

    const int* esrc = eidx;
    const int* edst = eidx + E;

    auto align = [](size_t v) { return (v + 255) & ~(size_t)255; };
    char* p = (char*)d_ws;
    int*   cnt    = (int*)p;   p += align((size_t)N * 4);
    unsigned short* sn = (unsigned short*)p; p += align((size_t)N * STRIDE * 2 + 64);
    _Float16* h1  = (_Float16*)p; p += align((size_t)N * 128 * 2);
    _Float16* h2  = (_Float16*)p; p += align((size_t)N * 128 * 2);
    _Float16* Wt1 = (_Float16*)p; p += align((size_t)128 * 160 * 2);
    _Float16* Wt2 = (_Float16*)p; p += align((size_t)128 * 128 * 2);
    float* as1    = (float*)p; p += align((size_t)N * 4);
    float* ad1    = (float*)p; p += align((size_t)N * 4);
    float* as2    = (float*)p; p += align((size_t)N * 4);
    float* ad2    = (float*)p; p += align((size_t)N * 4);
    (void)ws_size; (void)n_in; (void)out_size;

    const int nbN = (N + BS - 1) / BS;
    const int nbA = (E + BS - 1) / BS;                 // edge-atomic blocks
    const int nbG = (N + 31) / 32;                     // 32-row tiles
    const int wblocks = (128 * 160 + 128 * 128 + BS - 1) / BS;

    k_init<<<nbN + wblocks, BS, 0, stream>>>(cnt, sn, W1, W2, Wt1, Wt2, N, nbN);
    k_scatter_gemm1<<<nbG + nbA, BS, 0, stream>>>(
        esrc, edst, cnt, sn, x_base, cell_ids, cell_emb, Wt1,
        a_src1, a_dst1, h1, as1, ad1, E, N, nbG, nbA);
    k_agg1_gemm2<<<nbG, 512, 0, stream>>>(
        h1, sn, cnt, as1, ad1, b1, ln_g, ln_b, Wt2,
        a_src2, a_dst2, h2, as2, ad2, N);
    k_agg2<<<(N + 15) / 16, BS, 0, stream>>>(
        h2, sn, cnt, as2, ad2, b2, (float*)d_out, N);
}